// Round 1
// baseline (18.379 us; speedup 1.0000x reference)
//
#include <hip/hip_runtime.h>

// DynamicSpatialEncoder: the reference's output is batch-independent.
// x starts as feat=Wp[0]+bp broadcast to (B,21,D); each GIN layer maps the
// (root,nbr) two-row structure to a new (root,nbr) pair, and BatchNorm stats
// over (B,21) collapse to the weighted two-point form. Output = final root
// row repeated B times.

#define D 128
#define BN_EPS 1e-5f

__global__ __launch_bounds__(256) void gin_compute_vec(
    const float* __restrict__ Wp,   const float* __restrict__ bp,
    const float* __restrict__ W1_0, const float* __restrict__ b1_0,
    const float* __restrict__ W2_0, const float* __restrict__ b2_0,
    const float* __restrict__ g0,   const float* __restrict__ be0,
    const float* __restrict__ W1_1, const float* __restrict__ b1_1,
    const float* __restrict__ W2_1, const float* __restrict__ b2_1,
    const float* __restrict__ g1,   const float* __restrict__ be1,
    float* __restrict__ ws)
{
    __shared__ float sIn[2][D];   // current (root, nbr) rows entering the layer
    __shared__ float sH[2][D];    // rows after neighbor aggregation
    __shared__ float sA[2][D];    // relu(h@W1+b1)
    __shared__ float sO[2][D];    // a@W2+b2

    const int tid = threadIdx.x;
    const int grp = tid >> 7;     // 0 = root row, 1 = nbr row (wave-uniform)
    const int d   = tid & (D - 1);

    // feat = ones(1) @ Wp + bp = Wp[0,:] + bp ; both rows start as feat
    sIn[grp][d] = Wp[d] + bp[d];
    __syncthreads();

    const float* W1s[2] = {W1_0, W1_1};
    const float* b1s[2] = {b1_0, b1_1};
    const float* W2s[2] = {W2_0, W2_1};
    const float* b2s[2] = {b2_0, b2_1};
    const float* gs [2] = {g0,   g1};
    const float* bes[2] = {be0,  be1};

    for (int layer = 0; layer < 2; ++layer) {
        const float* __restrict__ W1 = W1s[layer];
        const float* __restrict__ b1 = b1s[layer];
        const float* __restrict__ W2 = W2s[layer];
        const float* __restrict__ b2 = b2s[layer];

        // h[:,0,:] = root + sum(nbrs) = root + 20*nbr ; h[:,j,:] = nbr + root
        if (grp == 0) sH[0][d] = sIn[0][d] + 20.0f * sIn[1][d];
        else          sH[1][d] = sIn[1][d] + sIn[0][d];
        __syncthreads();

        // a = relu(h @ W1 + b1)   (thread d computes output channel d)
        float acc = b1[d];
        #pragma unroll 8
        for (int i = 0; i < D; ++i) acc = fmaf(sH[grp][i], W1[i * D + d], acc);
        sA[grp][d] = fmaxf(acc, 0.0f);
        __syncthreads();

        // o = a @ W2 + b2
        acc = b2[d];
        #pragma unroll 8
        for (int i = 0; i < D; ++i) acc = fmaf(sA[grp][i], W2[i * D + d], acc);
        sO[grp][d] = acc;
        __syncthreads();

        // BatchNorm over (B,21): two-point weighted stats, numerically stable form
        float hr = sO[0][d], hn = sO[1][d];
        float mean = (hr + 20.0f * hn) * (1.0f / 21.0f);
        float dr = hr - mean, dn = hn - mean;
        float var = (dr * dr + 20.0f * dn * dn) * (1.0f / 21.0f);
        float inv = rsqrtf(var + BN_EPS);
        float scale = gs[layer][d], shift = bes[layer][d];
        float mine = (grp == 0 ? dr : dn);
        sIn[grp][d] = mine * inv * scale + shift;
        __syncthreads();
    }

    if (tid < D) ws[tid] = sIn[0][tid];
}

__global__ __launch_bounds__(256) void broadcast_rows(
    const float4* __restrict__ ws4, float4* __restrict__ out4, int n4)
{
    int idx = blockIdx.x * blockDim.x + threadIdx.x;
    if (idx < n4) out4[idx] = ws4[idx & (D / 4 - 1)];
}

extern "C" void kernel_launch(void* const* d_in, const int* in_sizes, int n_in,
                              void* d_out, int out_size, void* d_ws, size_t ws_size,
                              hipStream_t stream) {
    // setup_inputs order:
    // 0 node_ids, 1 node_interact_times, 2 neighbor_nodes (all unused),
    // 3 Wp, 4 bp, 5 W1_0, 6 b1_0, 7 W2_0, 8 b2_0, 9 g0, 10 be0,
    // 11 W1_1, 12 b1_1, 13 W2_1, 14 b2_1, 15 g1, 16 be1
    const float* Wp   = (const float*)d_in[3];
    const float* bp   = (const float*)d_in[4];
    const float* W1_0 = (const float*)d_in[5];
    const float* b1_0 = (const float*)d_in[6];
    const float* W2_0 = (const float*)d_in[7];
    const float* b2_0 = (const float*)d_in[8];
    const float* g0   = (const float*)d_in[9];
    const float* be0  = (const float*)d_in[10];
    const float* W1_1 = (const float*)d_in[11];
    const float* b1_1 = (const float*)d_in[12];
    const float* W2_1 = (const float*)d_in[13];
    const float* b2_1 = (const float*)d_in[14];
    const float* g1   = (const float*)d_in[15];
    const float* be1  = (const float*)d_in[16];

    float* ws = (float*)d_ws;

    gin_compute_vec<<<1, 256, 0, stream>>>(
        Wp, bp, W1_0, b1_0, W2_0, b2_0, g0, be0,
        W1_1, b1_1, W2_1, b2_1, g1, be1, ws);

    int n4 = out_size / 4;                 // 16384*128/4 = 524288 float4 stores
    int blocks = (n4 + 255) / 256;         // 2048 blocks, exactly 1 store/thread
    broadcast_rows<<<blocks, 256, 0, stream>>>(
        (const float4*)ws, (float4*)d_out, n4);
}

// Round 2
// 14.571 us; speedup vs baseline: 1.2613x; 1.2613x over previous
//
#include <hip/hip_runtime.h>

// DynamicSpatialEncoder: reference output is batch-independent.
// x starts as feat=Wp[0]+bp broadcast to (B,21,D); each GIN layer maps the
// (root,nbr) two-row structure to a new (root,nbr) pair; BatchNorm over (B,21)
// collapses to weighted two-point stats. Output = final root row repeated B.
//
// Fused single kernel: every block redundantly computes the 128-float root
// vector (131 KFLOP, weights L2-cached after first wave), then stores its
// grid-stride slice of the 8 MB output. One launch, no cross-kernel dep.

#define D 128
#define BN_EPS 1e-5f
#define NBLK 256
#define NTHR 256

__global__ __launch_bounds__(NTHR) void gin_fused(
    const float* __restrict__ Wp,   const float* __restrict__ bp,
    const float* __restrict__ W1_0, const float* __restrict__ b1_0,
    const float* __restrict__ W2_0, const float* __restrict__ b2_0,
    const float* __restrict__ g0,   const float* __restrict__ be0,
    const float* __restrict__ W1_1, const float* __restrict__ b1_1,
    const float* __restrict__ W2_1, const float* __restrict__ b2_1,
    const float* __restrict__ g1,   const float* __restrict__ be1,
    float4* __restrict__ out4, int n4)
{
    __shared__ float sIn[2][D];   // (root, nbr) rows entering the layer
    __shared__ float sH[2][D];    // rows after neighbor aggregation
    __shared__ float sA[2][D];    // relu(h@W1+b1)
    __shared__ float sO[2][D];    // a@W2+b2

    const int tid = threadIdx.x;
    const int grp = tid >> 7;     // 0 = root row, 1 = nbr row (wave-uniform)
    const int d   = tid & (D - 1);

    // feat = ones(1) @ Wp + bp ; both rows start as feat
    sIn[grp][d] = Wp[d] + bp[d];
    __syncthreads();

    const float* W1s[2] = {W1_0, W1_1};
    const float* b1s[2] = {b1_0, b1_1};
    const float* W2s[2] = {W2_0, W2_1};
    const float* b2s[2] = {b2_0, b2_1};
    const float* gs [2] = {g0,   g1};
    const float* bes[2] = {be0,  be1};

    for (int layer = 0; layer < 2; ++layer) {
        const float* __restrict__ W1 = W1s[layer];
        const float* __restrict__ b1 = b1s[layer];
        const float* __restrict__ W2 = W2s[layer];
        const float* __restrict__ b2 = b2s[layer];

        // h[:,0,:] = root + 20*nbr ; h[:,j,:] = nbr + root
        if (grp == 0) sH[0][d] = sIn[0][d] + 20.0f * sIn[1][d];
        else          sH[1][d] = sIn[1][d] + sIn[0][d];
        __syncthreads();

        // a = relu(h @ W1 + b1)  (thread d -> output channel d; coalesced col reads)
        float acc = b1[d];
        #pragma unroll 16
        for (int i = 0; i < D; ++i) acc = fmaf(sH[grp][i], W1[i * D + d], acc);
        sA[grp][d] = fmaxf(acc, 0.0f);
        __syncthreads();

        // o = a @ W2 + b2
        acc = b2[d];
        #pragma unroll 16
        for (int i = 0; i < D; ++i) acc = fmaf(sA[grp][i], W2[i * D + d], acc);
        sO[grp][d] = acc;
        __syncthreads();

        // BatchNorm over (B,21): stable two-point weighted stats
        float hr = sO[0][d], hn = sO[1][d];
        float mean = (hr + 20.0f * hn) * (1.0f / 21.0f);
        float dr = hr - mean, dn = hn - mean;
        float var = (dr * dr + 20.0f * dn * dn) * (1.0f / 21.0f);
        float inv = rsqrtf(var + BN_EPS);
        float mine = (grp == 0 ? dr : dn);
        sIn[grp][d] = mine * inv * gs[layer][d] + bes[layer][d];
        __syncthreads();
    }

    // Broadcast store. gid stride = NBLK*NTHR = 65536, a multiple of 32, so
    // (gid + k*stride) & 31 is constant per thread: one register float4,
    // stored 8 times, fully coalesced.
    const int gid = blockIdx.x * NTHR + tid;
    const float4 val = ((const float4*)sIn[0])[tid & 31];
    for (int i = gid; i < n4; i += NBLK * NTHR) out4[i] = val;
}

extern "C" void kernel_launch(void* const* d_in, const int* in_sizes, int n_in,
                              void* d_out, int out_size, void* d_ws, size_t ws_size,
                              hipStream_t stream) {
    // inputs: 0 node_ids, 1 times, 2 neighbors (unused),
    // 3 Wp, 4 bp, 5 W1_0, 6 b1_0, 7 W2_0, 8 b2_0, 9 g0, 10 be0,
    // 11 W1_1, 12 b1_1, 13 W2_1, 14 b2_1, 15 g1, 16 be1
    const float* Wp   = (const float*)d_in[3];
    const float* bp   = (const float*)d_in[4];
    const float* W1_0 = (const float*)d_in[5];
    const float* b1_0 = (const float*)d_in[6];
    const float* W2_0 = (const float*)d_in[7];
    const float* b2_0 = (const float*)d_in[8];
    const float* g0   = (const float*)d_in[9];
    const float* be0  = (const float*)d_in[10];
    const float* W1_1 = (const float*)d_in[11];
    const float* b1_1 = (const float*)d_in[12];
    const float* W2_1 = (const float*)d_in[13];
    const float* b2_1 = (const float*)d_in[14];
    const float* g1   = (const float*)d_in[15];
    const float* be1  = (const float*)d_in[16];

    int n4 = out_size / 4;  // 524288 float4
    gin_fused<<<NBLK, NTHR, 0, stream>>>(
        Wp, bp, W1_0, b1_0, W2_0, b2_0, g0, be0,
        W1_1, b1_1, W2_1, b2_1, g1, be1,
        (float4*)d_out, n4);
}

// Round 3
// 12.365 us; speedup vs baseline: 1.4864x; 1.1784x over previous
//
#include <hip/hip_runtime.h>

// DynamicSpatialEncoder: reference output is batch-independent.
// x starts as feat=Wp[0]+bp broadcast to (B,21,D); each GIN layer maps the
// (root,nbr) two-row structure to a new (root,nbr) pair; BatchNorm over (B,21)
// collapses to weighted two-point stats. Output = final root row repeated B.
//
// Fused single kernel, 256 blocks: every block redundantly computes the
// 128-float root vector, then stores its slice of the 8 MB output.
// Matvec structure: thread t owns col-group cg=t&31 (4 cols, float4 loads)
// and K-slice sl=t>>5 (16 of 128 i's) -> 16 independent float4 loads per
// matvec (ONE latency round), both rows computed from the same weights,
// 8-way split-K reduced through LDS.

#define D 128
#define BN_EPS 1e-5f
#define NBLK 256
#define NTHR 256

__device__ __forceinline__ void matvec_pair(
    const float* __restrict__ W,
    const float (&in)[2][D],
    float (&red)[8][2][D],
    int cg, int sl)
{
    const float4* __restrict__ W4 = (const float4*)W;
    float4 aR = make_float4(0.f, 0.f, 0.f, 0.f);
    float4 aN = make_float4(0.f, 0.f, 0.f, 0.f);
    #pragma unroll
    for (int k = 0; k < 16; ++k) {
        const int i = sl * 16 + k;
        const float4 w = W4[i * 32 + cg];   // 512B contiguous per half-wave
        const float hr = in[0][i];          // LDS broadcast (same addr/lane)
        const float hn = in[1][i];
        aR.x = fmaf(hr, w.x, aR.x);
        aR.y = fmaf(hr, w.y, aR.y);
        aR.z = fmaf(hr, w.z, aR.z);
        aR.w = fmaf(hr, w.w, aR.w);
        aN.x = fmaf(hn, w.x, aN.x);
        aN.y = fmaf(hn, w.y, aN.y);
        aN.z = fmaf(hn, w.z, aN.z);
        aN.w = fmaf(hn, w.w, aN.w);
    }
    ((float4*)&red[sl][0][0])[cg] = aR;     // contiguous 512B per half-wave
    ((float4*)&red[sl][1][0])[cg] = aN;
}

__global__ __launch_bounds__(NTHR) void gin_fused(
    const float* __restrict__ Wp,   const float* __restrict__ bp,
    const float* __restrict__ W1_0, const float* __restrict__ b1_0,
    const float* __restrict__ W2_0, const float* __restrict__ b2_0,
    const float* __restrict__ g0,   const float* __restrict__ be0,
    const float* __restrict__ W1_1, const float* __restrict__ b1_1,
    const float* __restrict__ W2_1, const float* __restrict__ b2_1,
    const float* __restrict__ g1,   const float* __restrict__ be1,
    float4* __restrict__ out4, int n4)
{
    __shared__ float sRow[2][D];     // rows entering each layer / final result
    __shared__ float sH[2][D];       // matvec input/output staging
    __shared__ float sRed[8][2][D];  // split-K partials (8 KB)

    const int tid = threadIdx.x;
    const int grp = tid >> 7;        // 0 = root row, 1 = nbr row
    const int d   = tid & (D - 1);
    const int cg  = tid & 31;        // column group (4 cols)
    const int sl  = tid >> 5;        // K-slice 0..7

    // feat = ones(1) @ Wp + bp ; both rows start as feat
    sRow[grp][d] = Wp[d] + bp[d];
    __syncthreads();

    const float* W1s[2] = {W1_0, W1_1};
    const float* b1s[2] = {b1_0, b1_1};
    const float* W2s[2] = {W2_0, W2_1};
    const float* b2s[2] = {b2_0, b2_1};
    const float* gs [2] = {g0,   g1};
    const float* bes[2] = {be0,  be1};

    #pragma unroll
    for (int layer = 0; layer < 2; ++layer) {
        const float* __restrict__ W1 = W1s[layer];
        const float* __restrict__ b1 = b1s[layer];
        const float* __restrict__ W2 = W2s[layer];
        const float* __restrict__ b2 = b2s[layer];

        // neighbor aggregation: root' = root + 20*nbr ; nbr' = nbr + root
        sH[grp][d] = (grp == 0) ? sRow[0][d] + 20.0f * sRow[1][d]
                                : sRow[1][d] + sRow[0][d];
        __syncthreads();

        // a = relu(h @ W1 + b1), both rows
        matvec_pair(W1, sH, sRed, cg, sl);
        __syncthreads();
        {
            float v = b1[d];
            #pragma unroll
            for (int s = 0; s < 8; ++s) v += sRed[s][grp][d];
            sH[grp][d] = fmaxf(v, 0.0f);   // sH reuse: matvec1 fully done
        }
        __syncthreads();

        // o = a @ W2 + b2, both rows
        matvec_pair(W2, sH, sRed, cg, sl);
        __syncthreads();
        {
            float v = b2[d];
            #pragma unroll
            for (int s = 0; s < 8; ++s) v += sRed[s][grp][d];
            sH[grp][d] = v;
        }
        __syncthreads();

        // BatchNorm over (B,21): stable two-point weighted stats
        {
            float hr = sH[0][d], hn = sH[1][d];
            float mean = (hr + 20.0f * hn) * (1.0f / 21.0f);
            float dr = hr - mean, dn = hn - mean;
            float var = (dr * dr + 20.0f * dn * dn) * (1.0f / 21.0f);
            float inv = rsqrtf(var + BN_EPS);
            float mine = (grp == 0 ? dr : dn);
            sRow[grp][d] = mine * inv * gs[layer][d] + bes[layer][d];
        }
        __syncthreads();
    }

    // Broadcast store: stride 65536 is a multiple of 32 -> each thread's
    // float4 is loop-invariant; 8 coalesced stores/thread cover 8 MB.
    const int gid = blockIdx.x * NTHR + tid;
    const float4 val = ((const float4*)sRow[0])[tid & 31];
    #pragma unroll
    for (int i = 0; i < 8; ++i) {
        int idx = gid + i * NBLK * NTHR;
        if (idx < n4) out4[idx] = val;
    }
}

extern "C" void kernel_launch(void* const* d_in, const int* in_sizes, int n_in,
                              void* d_out, int out_size, void* d_ws, size_t ws_size,
                              hipStream_t stream) {
    // inputs: 0 node_ids, 1 times, 2 neighbors (unused),
    // 3 Wp, 4 bp, 5 W1_0, 6 b1_0, 7 W2_0, 8 b2_0, 9 g0, 10 be0,
    // 11 W1_1, 12 b1_1, 13 W2_1, 14 b2_1, 15 g1, 16 be1
    const float* Wp   = (const float*)d_in[3];
    const float* bp   = (const float*)d_in[4];
    const float* W1_0 = (const float*)d_in[5];
    const float* b1_0 = (const float*)d_in[6];
    const float* W2_0 = (const float*)d_in[7];
    const float* b2_0 = (const float*)d_in[8];
    const float* g0   = (const float*)d_in[9];
    const float* be0  = (const float*)d_in[10];
    const float* W1_1 = (const float*)d_in[11];
    const float* b1_1 = (const float*)d_in[12];
    const float* W2_1 = (const float*)d_in[13];
    const float* b2_1 = (const float*)d_in[14];
    const float* g1   = (const float*)d_in[15];
    const float* be1  = (const float*)d_in[16];

    int n4 = out_size / 4;  // 524288 float4
    gin_fused<<<NBLK, NTHR, 0, stream>>>(
        Wp, bp, W1_0, b1_0, W2_0, b2_0, g0, be0,
        W1_1, b1_1, W2_1, b2_1, g1, be1,
        (float4*)d_out, n4);
}

// Round 5
// 11.439 us; speedup vs baseline: 1.6066x; 1.0809x over previous
//
#include <hip/hip_runtime.h>

// DynamicSpatialEncoder: reference output is batch-independent.
// x starts as feat=Wp[0]+bp broadcast to (B,21,D); each GIN layer maps the
// (root,nbr) two-row structure to a new (root,nbr) pair; BatchNorm over (B,21)
// collapses to weighted two-point stats. Output = final root row repeated B.
//
// Single fused kernel, 256 blocks (1/CU): every block redundantly computes the
// 128-float root vector, then stores its slice of the 8 MB output.
// Key structure: ALL weight loads (64 float4/thread = 256 KB/block) are
// data-independent -> issued as ONE burst at kernel entry into registers
// (launch_bounds(256,1) allows ~300 VGPRs at our fixed 1-block/CU occupancy).
// Matvecs 2-4 then run with zero global-load latency; the serial chain is
// just fma + LDS split-K reduce + barriers, overlapped with the weight stream.

#define D 128
#define BN_EPS 1e-5f
#define NBLK 256
#define NTHR 256

typedef float f4 __attribute__((ext_vector_type(4)));  // clang vector: ok for nontemporal builtins

// One matvec for both rows from register-resident weights.
// Thread owns cols 4*cg..4*cg+3 and K-slice sl (i = sl*16..sl*16+15).
__device__ __forceinline__ void mv_pair_reg(
    const f4 (&w)[16],
    const float (&in)[2][D],
    float (&red)[8][2][D],
    int cg, int sl)
{
    f4 aR = (f4)(0.f);
    f4 aN = (f4)(0.f);
    #pragma unroll
    for (int k = 0; k < 16; ++k) {
        const int i = sl * 16 + k;
        const float hr = in[0][i];      // LDS broadcast (uniform addr per lane group)
        const float hn = in[1][i];
        aR.x = fmaf(hr, w[k].x, aR.x);
        aR.y = fmaf(hr, w[k].y, aR.y);
        aR.z = fmaf(hr, w[k].z, aR.z);
        aR.w = fmaf(hr, w[k].w, aR.w);
        aN.x = fmaf(hn, w[k].x, aN.x);
        aN.y = fmaf(hn, w[k].y, aN.y);
        aN.z = fmaf(hn, w[k].z, aN.z);
        aN.w = fmaf(hn, w[k].w, aN.w);
    }
    ((f4*)&red[sl][0][0])[cg] = aR;     // contiguous 512 B per half-wave
    ((f4*)&red[sl][1][0])[cg] = aN;
}

__global__ __launch_bounds__(NTHR, 1) void gin_fused(
    const float* __restrict__ Wp,   const float* __restrict__ bp,
    const float* __restrict__ W1_0, const float* __restrict__ b1_0,
    const float* __restrict__ W2_0, const float* __restrict__ b2_0,
    const float* __restrict__ g0,   const float* __restrict__ be0,
    const float* __restrict__ W1_1, const float* __restrict__ b1_1,
    const float* __restrict__ W2_1, const float* __restrict__ b2_1,
    const float* __restrict__ g1,   const float* __restrict__ be1,
    f4* __restrict__ out4, int n4)
{
    __shared__ float sRow[2][D];     // rows entering each layer / final result
    __shared__ float sH[2][D];       // matvec input/output staging
    __shared__ float sRed[8][2][D];  // split-K partials (8 KB)

    const int tid = threadIdx.x;
    const int grp = tid >> 7;        // 0 = root row, 1 = nbr row
    const int d   = tid & (D - 1);
    const int cg  = tid & 31;        // column group (4 cols)
    const int sl  = tid >> 5;        // K-slice 0..7

    // ---- issue the ENTIRE load burst up front (no data deps) ----
    const float fWp = Wp[d];
    const float fbp = bp[d];

    f4 w10[16], w20[16], w11[16], w21[16];
    {
        const f4* __restrict__ p10 = (const f4*)W1_0 + cg;
        const f4* __restrict__ p20 = (const f4*)W2_0 + cg;
        const f4* __restrict__ p11 = (const f4*)W1_1 + cg;
        const f4* __restrict__ p21 = (const f4*)W2_1 + cg;
        #pragma unroll
        for (int k = 0; k < 16; ++k) w10[k] = p10[(sl * 16 + k) * 32];
        #pragma unroll
        for (int k = 0; k < 16; ++k) w20[k] = p20[(sl * 16 + k) * 32];
        #pragma unroll
        for (int k = 0; k < 16; ++k) w11[k] = p11[(sl * 16 + k) * 32];
        #pragma unroll
        for (int k = 0; k < 16; ++k) w21[k] = p21[(sl * 16 + k) * 32];
    }
    const float fb1_0 = b1_0[d], fb2_0 = b2_0[d], fg0 = g0[d], fbe0 = be0[d];
    const float fb1_1 = b1_1[d], fb2_1 = b2_1[d], fg1 = g1[d], fbe1 = be1[d];

    // feat = ones(1) @ Wp + bp ; both rows start as feat
    sRow[grp][d] = fWp + fbp;
    __syncthreads();

    const float fb1[2] = {fb1_0, fb1_1};
    const float fb2[2] = {fb2_0, fb2_1};
    const float fg [2] = {fg0,  fg1};
    const float fbe[2] = {fbe0, fbe1};

    #pragma unroll
    for (int layer = 0; layer < 2; ++layer) {
        // neighbor aggregation: root' = root + 20*nbr ; nbr' = nbr + root
        sH[grp][d] = (grp == 0) ? sRow[0][d] + 20.0f * sRow[1][d]
                                : sRow[1][d] + sRow[0][d];
        __syncthreads();

        // a = relu(h @ W1 + b1), both rows (register weights)
        if (layer == 0) mv_pair_reg(w10, sH, sRed, cg, sl);
        else            mv_pair_reg(w11, sH, sRed, cg, sl);
        __syncthreads();
        {
            float v = fb1[layer];
            #pragma unroll
            for (int s = 0; s < 8; ++s) v += sRed[s][grp][d];
            sH[grp][d] = fmaxf(v, 0.0f);
        }
        __syncthreads();

        // o = a @ W2 + b2, both rows
        if (layer == 0) mv_pair_reg(w20, sH, sRed, cg, sl);
        else            mv_pair_reg(w21, sH, sRed, cg, sl);
        __syncthreads();
        {
            float v = fb2[layer];
            #pragma unroll
            for (int s = 0; s < 8; ++s) v += sRed[s][grp][d];
            sH[grp][d] = v;
        }
        __syncthreads();

        // BatchNorm over (B,21): stable two-point weighted stats
        {
            float hr = sH[0][d], hn = sH[1][d];
            float mean = (hr + 20.0f * hn) * (1.0f / 21.0f);
            float dr = hr - mean, dn = hn - mean;
            float var = (dr * dr + 20.0f * dn * dn) * (1.0f / 21.0f);
            float inv = rsqrtf(var + BN_EPS);
            float mine = (grp == 0 ? dr : dn);
            sRow[grp][d] = mine * inv * fg[layer] + fbe[layer];
        }
        __syncthreads();
    }

    // Broadcast store: stride 65536 is a multiple of 32 -> each thread's
    // f4 is loop-invariant; 8 coalesced nontemporal stores cover 8 MB.
    const int gid = blockIdx.x * NTHR + tid;
    const f4 val = ((const f4*)sRow[0])[tid & 31];
    #pragma unroll
    for (int i = 0; i < 8; ++i) {
        int idx = gid + i * NBLK * NTHR;
        if (idx < n4) __builtin_nontemporal_store(val, &out4[idx]);
    }
}

extern "C" void kernel_launch(void* const* d_in, const int* in_sizes, int n_in,
                              void* d_out, int out_size, void* d_ws, size_t ws_size,
                              hipStream_t stream) {
    // inputs: 0 node_ids, 1 times, 2 neighbors (unused),
    // 3 Wp, 4 bp, 5 W1_0, 6 b1_0, 7 W2_0, 8 b2_0, 9 g0, 10 be0,
    // 11 W1_1, 12 b1_1, 13 W2_1, 14 b2_1, 15 g1, 16 be1
    const float* Wp   = (const float*)d_in[3];
    const float* bp   = (const float*)d_in[4];
    const float* W1_0 = (const float*)d_in[5];
    const float* b1_0 = (const float*)d_in[6];
    const float* W2_0 = (const float*)d_in[7];
    const float* b2_0 = (const float*)d_in[8];
    const float* g0   = (const float*)d_in[9];
    const float* be0  = (const float*)d_in[10];
    const float* W1_1 = (const float*)d_in[11];
    const float* b1_1 = (const float*)d_in[12];
    const float* W2_1 = (const float*)d_in[13];
    const float* b2_1 = (const float*)d_in[14];
    const float* g1   = (const float*)d_in[15];
    const float* be1  = (const float*)d_in[16];

    int n4 = out_size / 4;  // 524288 float4
    gin_fused<<<NBLK, NTHR, 0, stream>>>(
        Wp, bp, W1_0, b1_0, W2_0, b2_0, g0, be0,
        W1_1, b1_1, W2_1, b2_1, g1, be1,
        (f4*)d_out, n4);
}

// Round 6
// 11.108 us; speedup vs baseline: 1.6546x; 1.0299x over previous
//
#include <hip/hip_runtime.h>

// DynamicSpatialEncoder: reference output is batch-independent (inputs to the
// GIN stack are a single broadcast feature row; BN collapses to two-point
// stats). Output = final root row repeated B=16384 times.
//
// Structure: 256 blocks (1/CU), each redundantly computes the 128-float root
// vector, then stores its slice of the 8 MB output.
//  - ALL weight loads (64 float4/thread) hoisted into registers, issued
//    earliest-needed-first.
//  - Barriers use raw `s_waitcnt lgkmcnt(0); s_barrier` so the global burst
//    is NOT drained at barriers (__syncthreads would emit vmcnt(0)) — loads
//    stream across phases, compiler inserts counted vmcnt waits per use.
//  - Layer-0 matvec input is analytic (21*feat / 2*feat), no initial barrier.

#define D 128
#define BN_EPS 1e-5f
#define NBLK 256
#define NTHR 256

typedef float f4 __attribute__((ext_vector_type(4)));

// Block barrier WITHOUT vmcnt drain: lgkmcnt(0) publishes this wave's LDS
// writes, s_barrier syncs; outstanding global loads stay in flight.
__device__ __forceinline__ void barrier_nodrain() {
    asm volatile("s_waitcnt lgkmcnt(0)\n\ts_barrier" ::: "memory");
}

// One matvec for both rows from register-resident weights.
// Thread owns cols 4*cg..4*cg+3 and K-slice sl (i = sl*16..sl*16+15).
__device__ __forceinline__ void mv_pair_reg(
    const f4 (&w)[16], const float (&in)[2][D], float (&red)[8][2][D],
    int cg, int sl)
{
    f4 aR = (f4)(0.f);
    f4 aN = (f4)(0.f);
    #pragma unroll
    for (int k = 0; k < 16; ++k) {
        const int i = sl * 16 + k;
        const float hr = in[0][i];   // LDS broadcast
        const float hn = in[1][i];
        aR.x = fmaf(hr, w[k].x, aR.x);
        aR.y = fmaf(hr, w[k].y, aR.y);
        aR.z = fmaf(hr, w[k].z, aR.z);
        aR.w = fmaf(hr, w[k].w, aR.w);
        aN.x = fmaf(hn, w[k].x, aN.x);
        aN.y = fmaf(hn, w[k].y, aN.y);
        aN.z = fmaf(hn, w[k].z, aN.z);
        aN.w = fmaf(hn, w[k].w, aN.w);
    }
    ((f4*)&red[sl][0][0])[cg] = aR;   // contiguous 512 B per half-wave
    ((f4*)&red[sl][1][0])[cg] = aN;
}

__global__ __launch_bounds__(NTHR, 1) void gin_fused(
    const float* __restrict__ Wp,   const float* __restrict__ bp,
    const float* __restrict__ W1_0, const float* __restrict__ b1_0,
    const float* __restrict__ W2_0, const float* __restrict__ b2_0,
    const float* __restrict__ g0,   const float* __restrict__ be0,
    const float* __restrict__ W1_1, const float* __restrict__ b1_1,
    const float* __restrict__ W2_1, const float* __restrict__ b2_1,
    const float* __restrict__ g1,   const float* __restrict__ be1,
    f4* __restrict__ out4, int n4)
{
    __shared__ float sA[2][D];       // staging ping
    __shared__ float sB[2][D];       // staging pong
    __shared__ float sRed[8][2][D];  // split-K partials (8 KB)
    __shared__ float sOut[D];        // final root row

    const int tid = threadIdx.x;
    const int grp = tid >> 7;        // 0 = root row, 1 = nbr row
    const int d   = tid & (D - 1);
    const int cg  = tid & 31;        // column group (4 cols)
    const int sl  = tid >> 5;        // K-slice 0..7

    // -------- load burst, earliest-needed-first --------
    f4 wp4[4], bpv[4];
    {
        const f4* __restrict__ pW = (const f4*)Wp + sl * 4;
        const f4* __restrict__ pB = (const f4*)bp + sl * 4;
        #pragma unroll
        for (int k = 0; k < 4; ++k) { wp4[k] = pW[k]; bpv[k] = pB[k]; }
    }
    f4 w10[16];
    {
        const f4* __restrict__ p = (const f4*)W1_0 + cg;
        #pragma unroll
        for (int k = 0; k < 16; ++k) w10[k] = p[(sl * 16 + k) * 32];
    }
    const float fb1_0 = b1_0[d], fb2_0 = b2_0[d], fg0 = g0[d], fbe0 = be0[d];
    const float fb1_1 = b1_1[d], fb2_1 = b2_1[d], fg1 = g1[d], fbe1 = be1[d];
    f4 w20[16], w11[16], w21[16];
    {
        const f4* __restrict__ p = (const f4*)W2_0 + cg;
        #pragma unroll
        for (int k = 0; k < 16; ++k) w20[k] = p[(sl * 16 + k) * 32];
    }
    {
        const f4* __restrict__ p = (const f4*)W1_1 + cg;
        #pragma unroll
        for (int k = 0; k < 16; ++k) w11[k] = p[(sl * 16 + k) * 32];
    }
    {
        const f4* __restrict__ p = (const f4*)W2_1 + cg;
        #pragma unroll
        for (int k = 0; k < 16; ++k) w21[k] = p[(sl * 16 + k) * 32];
    }

    // -------- layer 0, matvec 1: input rows are analytic --------
    // feat = Wp + bp ; h_root = 21*feat ; h_nbr = 2*feat
    {
        f4 aR = (f4)(0.f);
        f4 aN = (f4)(0.f);
        #pragma unroll
        for (int k = 0; k < 16; ++k) {
            const float f  = wp4[k >> 2][k & 3] + bpv[k >> 2][k & 3];
            const float hr = 21.0f * f;
            const float hn = 2.0f * f;
            aR.x = fmaf(hr, w10[k].x, aR.x);
            aR.y = fmaf(hr, w10[k].y, aR.y);
            aR.z = fmaf(hr, w10[k].z, aR.z);
            aR.w = fmaf(hr, w10[k].w, aR.w);
            aN.x = fmaf(hn, w10[k].x, aN.x);
            aN.y = fmaf(hn, w10[k].y, aN.y);
            aN.z = fmaf(hn, w10[k].z, aN.z);
            aN.w = fmaf(hn, w10[k].w, aN.w);
        }
        ((f4*)&sRed[sl][0][0])[cg] = aR;
        ((f4*)&sRed[sl][1][0])[cg] = aN;
    }
    barrier_nodrain();

    // reduce + bias + relu -> sA
    {
        float v = fb1_0;
        #pragma unroll
        for (int s = 0; s < 8; ++s) v += sRed[s][grp][d];
        sA[grp][d] = fmaxf(v, 0.0f);
    }
    barrier_nodrain();

    mv_pair_reg(w20, sA, sRed, cg, sl);
    barrier_nodrain();

    // reduce + bias -> sB  (pre-BN output of layer 0)
    {
        float v = fb2_0;
        #pragma unroll
        for (int s = 0; s < 8; ++s) v += sRed[s][grp][d];
        sB[grp][d] = v;
    }
    barrier_nodrain();

    // BN0 (two-point stats) fused with neighbor aggregation -> sA
    {
        const float hr = sB[0][d], hn = sB[1][d];
        const float mean = (hr + 20.0f * hn) * (1.0f / 21.0f);
        const float dr = hr - mean, dn = hn - mean;
        const float var = (dr * dr + 20.0f * dn * dn) * (1.0f / 21.0f);
        const float inv = rsqrtf(var + BN_EPS);
        const float bnR = dr * inv * fg0 + fbe0;
        const float bnN = dn * inv * fg0 + fbe0;
        sA[grp][d] = (grp == 0) ? bnR + 20.0f * bnN : bnN + bnR;
    }
    barrier_nodrain();

    mv_pair_reg(w11, sA, sRed, cg, sl);
    barrier_nodrain();

    // reduce + bias + relu -> sB
    {
        float v = fb1_1;
        #pragma unroll
        for (int s = 0; s < 8; ++s) v += sRed[s][grp][d];
        sB[grp][d] = fmaxf(v, 0.0f);
    }
    barrier_nodrain();

    mv_pair_reg(w21, sB, sRed, cg, sl);
    barrier_nodrain();

    // reduce + bias -> sA  (pre-BN output of layer 1)
    {
        float v = fb2_1;
        #pragma unroll
        for (int s = 0; s < 8; ++s) v += sRed[s][grp][d];
        sA[grp][d] = v;
    }
    barrier_nodrain();

    // BN1, root row only -> sOut
    if (grp == 0) {
        const float hr = sA[0][d], hn = sA[1][d];
        const float mean = (hr + 20.0f * hn) * (1.0f / 21.0f);
        const float dr = hr - mean, dn = hn - mean;
        const float var = (dr * dr + 20.0f * dn * dn) * (1.0f / 21.0f);
        const float inv = rsqrtf(var + BN_EPS);
        sOut[d] = dr * inv * fg1 + fbe1;
    }
    barrier_nodrain();

    // Broadcast store: stride 65536 is a multiple of 32 -> loop-invariant f4,
    // 8 coalesced nontemporal stores/thread cover the 8 MB output.
    const int gid = blockIdx.x * NTHR + tid;
    const f4 val = ((const f4*)sOut)[cg];
    #pragma unroll
    for (int i = 0; i < 8; ++i) {
        const int idx = gid + i * NBLK * NTHR;
        if (idx < n4) __builtin_nontemporal_store(val, &out4[idx]);
    }
}

extern "C" void kernel_launch(void* const* d_in, const int* in_sizes, int n_in,
                              void* d_out, int out_size, void* d_ws, size_t ws_size,
                              hipStream_t stream) {
    // inputs: 0 node_ids, 1 times, 2 neighbors (unused),
    // 3 Wp, 4 bp, 5 W1_0, 6 b1_0, 7 W2_0, 8 b2_0, 9 g0, 10 be0,
    // 11 W1_1, 12 b1_1, 13 W2_1, 14 b2_1, 15 g1, 16 be1
    const float* Wp   = (const float*)d_in[3];
    const float* bp   = (const float*)d_in[4];
    const float* W1_0 = (const float*)d_in[5];
    const float* b1_0 = (const float*)d_in[6];
    const float* W2_0 = (const float*)d_in[7];
    const float* b2_0 = (const float*)d_in[8];
    const float* g0   = (const float*)d_in[9];
    const float* be0  = (const float*)d_in[10];
    const float* W1_1 = (const float*)d_in[11];
    const float* b1_1 = (const float*)d_in[12];
    const float* W2_1 = (const float*)d_in[13];
    const float* b2_1 = (const float*)d_in[14];
    const float* g1   = (const float*)d_in[15];
    const float* be1  = (const float*)d_in[16];

    int n4 = out_size / 4;  // 524288 float4
    gin_fused<<<NBLK, NTHR, 0, stream>>>(
        Wp, bp, W1_0, b1_0, W2_0, b2_0, g0, be0,
        W1_1, b1_1, W2_1, b2_1, g1, be1,
        (f4*)d_out, n4);
}